// Round 5
// baseline (177.036 us; speedup 1.0000x reference)
//
#include <hip/hip_runtime.h>
#include <hip/hip_bf16.h>

#define N_NODES 100000
#define N_EDGES 250000
#define EMB 32
#define TYPES 16
#define R2 100          // num relations
#define SB 1024
#define NB ((N_EDGES + SB - 1) / SB)    // 245
#define CAP 4096        // per-relation slot capacity (counts ~2500±50)
#define S1 64           // stripes per relation, layer 1
#define S2 64           // stripes per relation, layer 2

typedef __attribute__((ext_vector_type(8))) short short8;
typedef __attribute__((ext_vector_type(4))) float f32x4;

// fp32 -> bf16 bits, round-to-nearest-even
__device__ __forceinline__ unsigned short f2bf_u(float f) {
    unsigned u = __float_as_uint(f);
    u = (u + 0x7fffu + ((u >> 16) & 1u)) >> 16;
    return (unsigned short)u;
}
// fire-and-forget device-scope fp32 atomic add (global_atomic_add_f32)
__device__ __forceinline__ void atomF(float* p, float v) {
    __hip_atomic_fetch_add(p, v, __ATOMIC_RELAXED, __HIP_MEMORY_SCOPE_AGENT);
}

#define ZBASE 2596128u          // u32 index of h1acc (zero region start)
#define ZN4   1200000u          // uint4 count: h1acc+h2acc = 4.8M u32 = 19.2MB

// ---------------------------------------------------------------------------
// Pass 1: blocks [0,NB) = edge scatter into relation buckets
//   (LDS ranks + one global atomicAdd per (block,rel)); degree count via dcnt.
//   epack = 8B/edge: {sid | d_lo15<<17, s | d_hi2<<17}.
// Blocks [NB,NB+R2) = W1/W2 bf16 fragment packing (pw1 = column pairs).
// ALL blocks: grid-stride zero of h1acc+h2acc (19.2MB) — consumed only by
//   later kernels, so no intra-kernel ordering needed.
__global__ __launch_bounds__(SB) void pass1_kernel(
        const int* __restrict__ etype, const int* __restrict__ edge_src,
        const int* __restrict__ edge_dst, const int* __restrict__ src_ids,
        const float* __restrict__ W1, const float* __restrict__ W2,
        int* __restrict__ rcnt, int* __restrict__ dcnt,
        unsigned short* __restrict__ pw1, unsigned short* __restrict__ pw2,
        uint2* __restrict__ epack, uint4* __restrict__ zbase) {
    int t = threadIdx.x, b = blockIdx.x;
    // zero accumulators (grid-stride over all 345 blocks)
    {
        uint4 z = {0u, 0u, 0u, 0u};
        for (unsigned i = b * SB + t; i < ZN4; i += (NB + R2) * SB)
            zbase[i] = z;
    }
    if (b < NB) {
        __shared__ int lh[R2];
        __shared__ int lbase[R2];
        if (t < R2) lh[t] = 0;
        __syncthreads();
        int e = b * SB + t;
        int r = 0, lrank = 0, d = 0, s = 0, sid = 0;
        bool valid = e < N_EDGES;
        if (valid) {
            r = etype[e];
            lrank = atomicAdd(&lh[r], 1);           // rank within (chunk, rel)
            d = edge_dst[e];
            atomicAdd(&dcnt[d], 1);                 // degree only
            s = edge_src[e];
            sid = src_ids[s];
        }
        __syncthreads();
        if (t < R2) {
            int c = lh[t];
            lbase[t] = c ? atomicAdd(&rcnt[t], c) : 0;
        }
        __syncthreads();
        if (valid) {
            uint2 v = { (unsigned)sid | (((unsigned)d & 0x7FFFu) << 17),
                        (unsigned)s   | (((unsigned)d >> 15) << 17) };
            epack[((size_t)r << 12) + lbase[r] + lrank] = v;
        }
    } else {
        int r = b - NB;
        // pack W1: b0 slot j<8 -> col 2n, b1 slot j>=8 -> col 2n+1; k = q*8+j
        const float* Wr1 = W1 + (size_t)r * (EMB * EMB);
        {
            int l = t >> 4, j = t & 15;
            int n = l & 15, q = l >> 4;
            int k = q * 8 + (j & 7);
            int col = (j < 8) ? (2 * n) : (2 * n + 1);
            pw1[(size_t)r * 1024 + t] = f2bf_u(Wr1[k * EMB + col]);
        }
        if (t < 512) {
            const float* Wr2 = W2 + (size_t)r * (EMB * TYPES);
            int l = t >> 3, j = t & 7;
            int n = l & 15, q = l >> 4;
            int k = q * 8 + j;
            pw2[(size_t)r * 512 + t] = f2bf_u(Wr2[k * TYPES + n]);
        }
    }
}

// ---------------------------------------------------------------------------
// Layer 1: gather entity rows in fp32 (32B/lane), convert to bf16 in-register,
// 2 MFMA/tile (cols 2n/2n+1), atomic-accumulate into dense h1acc[node][32].
__global__ __launch_bounds__(64) void layer1_kernel(
        const float* __restrict__ entity,
        const unsigned short* __restrict__ pw1,
        const int* __restrict__ rcnt,
        const uint2* __restrict__ epack,
        float* __restrict__ h1acc) {
    int r = blockIdx.x % R2, stripe = blockIdx.x / R2;
    int cnt = rcnt[r];
    int nT = (cnt + 15) >> 4;
    int lane = threadIdx.x;
    int n = lane & 15, q = lane >> 4;
    const unsigned short* pw = pw1 + (size_t)r * 1024;
    short8 b0 = *(const short8*)(pw + lane * 16);
    short8 b1 = *(const short8*)(pw + lane * 16 + 8);
    const uint2* ep = epack + ((size_t)r << 12);
    for (int g = stripe; g < nT; g += S1) {
        int base = g * 16;
        int cl = cnt - base;
        int me = n < cl ? n : cl - 1;
        uint2 E = ep[base + me];
        int sid = (int)(E.x & 0x1FFFFu);
        int d   = (int)((E.x >> 17) | ((E.y >> 17) << 15));
        const float4* ar = (const float4*)(entity + (size_t)sid * EMB + q * 8);
        float4 v0 = ar[0], v1 = ar[1];
        short8 a;
        a[0] = (short)f2bf_u(v0.x); a[1] = (short)f2bf_u(v0.y);
        a[2] = (short)f2bf_u(v0.z); a[3] = (short)f2bf_u(v0.w);
        a[4] = (short)f2bf_u(v1.x); a[5] = (short)f2bf_u(v1.y);
        a[6] = (short)f2bf_u(v1.z); a[7] = (short)f2bf_u(v1.w);
        f32x4 c0 = {0.f,0.f,0.f,0.f}, c1 = {0.f,0.f,0.f,0.f};
        c0 = __builtin_amdgcn_mfma_f32_16x16x32_bf16(a, b0, c0, 0, 0, 0);
        c1 = __builtin_amdgcn_mfma_f32_16x16x32_bf16(a, b1, c1, 0, 0, 0);
#pragma unroll
        for (int i = 0; i < 4; ++i) {
            int row = q * 4 + i;
            int dd = __shfl(d, row);            // lanes 0..15 hold rows 0..15
            if (row < cl) {
                float* hp = h1acc + (size_t)dd * EMB + 2 * n;
                atomF(hp,     c0[i]);           // col 2n
                atomF(hp + 1, c1[i]);           // col 2n+1
            }
        }
    }
}

// ---------------------------------------------------------------------------
// Reduce 1: pure streaming — mean + relu over dense fp32 acc -> h1 bf16x2.
__global__ void reduce1_kernel(const float* __restrict__ h1acc,
                               const int* __restrict__ dcnt,
                               unsigned int* __restrict__ h1bf) {
    int t = blockIdx.x * blockDim.x + threadIdx.x;   // over N_NODES*16
    if (t >= N_NODES * 16) return;
    int nn = t >> 4;
    float2 v = ((const float2*)h1acc)[t];            // cols (2cp, 2cp+1)
    float inv = 1.0f / fmaxf((float)dcnt[nn], 1.0f);
    unsigned lo = f2bf_u(fmaxf(v.x * inv, 0.f));
    unsigned hi = f2bf_u(fmaxf(v.y * inv, 0.f));
    h1bf[t] = lo | (hi << 16);
}

// ---------------------------------------------------------------------------
// Layer 2: gather bf16 h1 rows (16B/lane), 1 MFMA/tile, atomic-accumulate
// into dense h2acc[node][16].
__global__ __launch_bounds__(64) void layer2_kernel(
        const unsigned short* __restrict__ h1bf,
        const unsigned short* __restrict__ pw2,
        const int* __restrict__ rcnt,
        const uint2* __restrict__ epack,
        float* __restrict__ h2acc) {
    int r = blockIdx.x % R2, stripe = blockIdx.x / R2;
    int cnt = rcnt[r];
    int nT = (cnt + 15) >> 4;
    int lane = threadIdx.x;
    int n = lane & 15, q = lane >> 4;
    short8 b = *(const short8*)(pw2 + (size_t)r * 512 + lane * 8);
    const uint2* ep = epack + ((size_t)r << 12);
    for (int g = stripe; g < nT; g += S2) {
        int base = g * 16;
        int cl = cnt - base;
        int me = n < cl ? n : cl - 1;
        uint2 E = ep[base + me];
        int s = (int)(E.y & 0x1FFFFu);
        int d = (int)((E.x >> 17) | ((E.y >> 17) << 15));
        short8 a = *(const short8*)(h1bf + (size_t)s * EMB + q * 8);
        f32x4 c = {0.f,0.f,0.f,0.f};
        c = __builtin_amdgcn_mfma_f32_16x16x32_bf16(a, b, c, 0, 0, 0);
#pragma unroll
        for (int i = 0; i < 4; ++i) {
            int row = q * 4 + i;
            int dd = __shfl(d, row);
            if (row < cl)
                atomF(h2acc + (size_t)dd * TYPES + n, c[i]);
        }
    }
}

// ---------------------------------------------------------------------------
// Reduce 2 + PonderNet head: streaming over dense h2acc, writes fp32 output.
__global__ void reduce2_head_kernel(const float* __restrict__ h2acc,
                                    const int* __restrict__ dcnt,
                                    const float* __restrict__ lw,
                                    const float* __restrict__ lb,
                                    float* __restrict__ out) {
    int nn = blockIdx.x * blockDim.x + threadIdx.x;
    if (nn >= N_NODES) return;
    const float4* hr = (const float4*)(h2acc + (size_t)nn * TYPES);
    float4 H[4] = { hr[0], hr[1], hr[2], hr[3] };
    float inv = 1.0f / fmaxf((float)dcnt[nn], 1.0f);
    float h[TYPES];
#pragma unroll
    for (int j = 0; j < 4; ++j) {
        h[4*j]   = H[j].x * inv; h[4*j+1] = H[j].y * inv;
        h[4*j+2] = H[j].z * inv; h[4*j+3] = H[j].w * inv;
    }
    float dot = 0.f;
#pragma unroll
    for (int j = 0; j < TYPES; ++j) dot += h[j] * lw[j];
    dot += lb[0];
    float lam = 1.0f / (1.0f + expf(-dot));

    float4* y0 = (float4*)(out + (size_t)nn * TYPES);
    float4* y1 = (float4*)(out + (size_t)N_NODES * TYPES + (size_t)nn * TYPES);
#pragma unroll
    for (int j = 0; j < 4; ++j) {
        float4 v = { h[4*j], h[4*j+1], h[4*j+2], h[4*j+3] };
        y0[j] = v; y1[j] = v;
    }
    out[(size_t)2 * N_NODES * TYPES + nn] = lam;
    out[(size_t)2 * N_NODES * TYPES + N_NODES + nn] = 1.0f - lam;
}

// ---------------------------------------------------------------------------
extern "C" void kernel_launch(void* const* d_in, const int* in_sizes, int n_in,
                              void* d_out, int out_size, void* d_ws, size_t ws_size,
                              hipStream_t stream) {
    const float* entity = (const float*)d_in[0];
    const float* W1     = (const float*)d_in[1];
    const float* W2     = (const float*)d_in[2];
    const float* lw     = (const float*)d_in[3];
    const float* lb     = (const float*)d_in[4];
    const int* src_ids  = (const int*)d_in[5];
    const int* edge_src = (const int*)d_in[6];
    const int* edge_dst = (const int*)d_in[7];
    const int* etype    = (const int*)d_in[8];
    float* out = (float*)d_out;

    // ws layout (u32 units, all 16B aligned)
    unsigned int* W = (unsigned int*)d_ws;
    int* dcnt   = (int*)(W + 0);              // 100000  (memset)
    int* rcnt   = (int*)(W + 100000);         // 128     (memset)
    uint2* epack = (uint2*)(W + 100128);      // R2*CAP uint2 = 819,200 u32
    unsigned short* pw1 = (unsigned short*)(W + 919328);  // 51,200 u32
    unsigned short* pw2 = (unsigned short*)(W + 970528);  // 25,600 u32
    unsigned int* h1bf  = W + 996128;         // 1.6M u32 (bf16 h1)
    float* h1acc = (float*)(W + ZBASE);       // 3.2M u32 (100k x 32 fp32)
    float* h2acc = (float*)(W + 5796128);     // 1.6M u32 (100k x 16 fp32)
    // total: 7,396,128 u32 = 29.6 MB (zero region = ZBASE..end, in-kernel)

    (void)hipMemsetAsync(d_ws, 0, 100128 * sizeof(int), stream);  // dcnt+rcnt

    pass1_kernel<<<NB + R2, SB, 0, stream>>>(etype, edge_src, edge_dst, src_ids,
                                             W1, W2, rcnt, dcnt, pw1, pw2, epack,
                                             (uint4*)(W + ZBASE));
    layer1_kernel<<<R2 * S1, 64, 0, stream>>>(entity, pw1, rcnt, epack, h1acc);
    reduce1_kernel<<<(N_NODES * 16 + 255) / 256, 256, 0, stream>>>(
        h1acc, dcnt, h1bf);
    layer2_kernel<<<R2 * S2, 64, 0, stream>>>((const unsigned short*)h1bf, pw2,
                                              rcnt, epack, h2acc);
    reduce2_head_kernel<<<(N_NODES + 255) / 256, 256, 0, stream>>>(
        h2acc, dcnt, lw, lb, out);
}

// Round 6
// 131.662 us; speedup vs baseline: 1.3446x; 1.3446x over previous
//
#include <hip/hip_runtime.h>
#include <hip/hip_bf16.h>

#define N_NODES 100000
#define N_EDGES 250000
#define EMB 32
#define TYPES 16
#define R2 100          // num relations
#define SB 1024
#define NB ((N_EDGES + SB - 1) / SB)    // 245
#define CAP 4096        // per-relation slot capacity (counts ~2500±50)
#define CAPD 16         // per-node slot capacity (Poisson(2.5): P(deg>16) ~ 1e-10)
#define S1 64           // stripes per relation, layer 1
#define S2 64           // stripes per relation, layer 2
#define LW 4            // waves per block in layer kernels (256 threads)

typedef __attribute__((ext_vector_type(8))) short short8;
typedef __attribute__((ext_vector_type(4))) float f32x4;

// fp32 -> bf16 bits, round-to-nearest-even
__device__ __forceinline__ unsigned short f2bf_u(float f) {
    unsigned u = __float_as_uint(f);
    u = (u + 0x7fffu + ((u >> 16) & 1u)) >> 16;
    return (unsigned short)u;
}
// unpack bf16 pair from u32
__device__ __forceinline__ float bfl(unsigned u) { return __uint_as_float(u << 16); }
__device__ __forceinline__ float bfh(unsigned u) { return __uint_as_float(u & 0xffff0000u); }

// ---------------------------------------------------------------------------
// Pass 1: blocks [0,NB) = edge scatter (LDS relation ranks + one global
// atomicAdd per (block,rel); dst slot = (d<<4)|drank via dcnt atomic).
// epack = 8B/edge: {sid | pd_lo15<<17, s | pd_hi6<<17}.
// Blocks [NB,NB+R2) = W1/W2 bf16 fragment packing (pw1 = column pairs).
__global__ __launch_bounds__(SB) void pass1_kernel(
        const int* __restrict__ etype, const int* __restrict__ edge_src,
        const int* __restrict__ edge_dst, const int* __restrict__ src_ids,
        const float* __restrict__ W1, const float* __restrict__ W2,
        int* __restrict__ rcnt, int* __restrict__ dcnt,
        unsigned short* __restrict__ pw1, unsigned short* __restrict__ pw2,
        uint2* __restrict__ epack) {
    int t = threadIdx.x, b = blockIdx.x;
    if (b < NB) {
        __shared__ int lh[R2];
        __shared__ int lbase[R2];
        if (t < R2) lh[t] = 0;
        __syncthreads();
        int e = b * SB + t;
        int r = 0, lrank = 0, pd = 0, s = 0, sid = 0;
        bool valid = e < N_EDGES;
        if (valid) {
            r = etype[e];
            lrank = atomicAdd(&lh[r], 1);           // rank within (chunk, rel)
            int d = edge_dst[e];
            int drank = atomicAdd(&dcnt[d], 1);     // global dst rank (order free)
            if (drank > CAPD - 1) drank = CAPD - 1; // safety clamp
            pd = (d << 4) | drank;                  // final msg slot, 21 bits
            s = edge_src[e];
            sid = src_ids[s];
        }
        __syncthreads();
        if (t < R2) {
            int c = lh[t];
            lbase[t] = c ? atomicAdd(&rcnt[t], c) : 0;
        }
        __syncthreads();
        if (valid) {
            uint2 v = { (unsigned)sid | (((unsigned)pd & 0x7FFFu) << 17),
                        (unsigned)s   | (((unsigned)pd >> 15) << 17) };
            epack[((size_t)r << 12) + lbase[r] + lrank] = v;
        }
    } else {
        int r = b - NB;
        // pack W1: b0 slot j<8 -> col 2n, b1 slot j>=8 -> col 2n+1; k = q*8+j
        const float* Wr1 = W1 + (size_t)r * (EMB * EMB);
        {
            int l = t >> 4, j = t & 15;
            int n = l & 15, q = l >> 4;
            int k = q * 8 + (j & 7);
            int col = (j < 8) ? (2 * n) : (2 * n + 1);
            pw1[(size_t)r * 1024 + t] = f2bf_u(Wr1[k * EMB + col]);
        }
        if (t < 512) {
            const float* Wr2 = W2 + (size_t)r * (EMB * TYPES);
            int l = t >> 3, j = t & 7;
            int n = l & 15, q = l >> 4;
            int k = q * 8 + j;
            pw2[(size_t)r * 512 + t] = f2bf_u(Wr2[k * TYPES + n]);
        }
    }
}

// ---------------------------------------------------------------------------
// Layer 1: 256-thread blocks (4 waves) so occupancy isn't capped by the
// 16-workgroup/CU limit (R5 counters: 64t blocks pinned at 48%).
// Wave w of block (r, sg) handles stripe sg*LW+w. Gather entity rows in fp32
// (32B/lane), convert to bf16 in-register, 2 MFMA/tile (cols 2n/2n+1),
// coalesced u32 stores to msg1 at direct slot pd.
__global__ __launch_bounds__(64 * LW) void layer1_kernel(
        const float* __restrict__ entity,
        const unsigned short* __restrict__ pw1,
        const int* __restrict__ rcnt,
        const uint2* __restrict__ epack,
        unsigned int* __restrict__ msg1) {
    int r = blockIdx.x % R2, sg = blockIdx.x / R2;
    int lane = threadIdx.x & 63, w = threadIdx.x >> 6;
    int stripe = sg * LW + w;
    int cnt = rcnt[r];
    int nT = (cnt + 15) >> 4;
    int n = lane & 15, q = lane >> 4;
    const unsigned short* pw = pw1 + (size_t)r * 1024;
    short8 b0 = *(const short8*)(pw + lane * 16);
    short8 b1 = *(const short8*)(pw + lane * 16 + 8);
    const uint2* ep = epack + ((size_t)r << 12);
    for (int g = stripe; g < nT; g += S1) {
        int base = g * 16;
        int cl = cnt - base;
        int me = n < cl ? n : cl - 1;
        uint2 E = ep[base + me];
        int sid = (int)(E.x & 0x1FFFFu);
        int pd  = (int)((E.x >> 17) | ((E.y >> 17) << 15));
        const float4* ar = (const float4*)(entity + (size_t)sid * EMB + q * 8);
        float4 v0 = ar[0], v1 = ar[1];
        short8 a;
        a[0] = (short)f2bf_u(v0.x); a[1] = (short)f2bf_u(v0.y);
        a[2] = (short)f2bf_u(v0.z); a[3] = (short)f2bf_u(v0.w);
        a[4] = (short)f2bf_u(v1.x); a[5] = (short)f2bf_u(v1.y);
        a[6] = (short)f2bf_u(v1.z); a[7] = (short)f2bf_u(v1.w);
        f32x4 c0 = {0.f,0.f,0.f,0.f}, c1 = {0.f,0.f,0.f,0.f};
        c0 = __builtin_amdgcn_mfma_f32_16x16x32_bf16(a, b0, c0, 0, 0, 0);
        c1 = __builtin_amdgcn_mfma_f32_16x16x32_bf16(a, b1, c1, 0, 0, 0);
#pragma unroll
        for (int i = 0; i < 4; ++i) {
            int row = q * 4 + i;
            int p = __shfl(pd, row);            // lanes 0..15 hold rows 0..15
            if (row < cl) {
                unsigned wv = (unsigned)f2bf_u(c0[i]) | ((unsigned)f2bf_u(c1[i]) << 16);
                msg1[(size_t)p * 16 + n] = wv;  // cols (2n, 2n+1), coalesced
            }
        }
    }
}

// ---------------------------------------------------------------------------
// Segmented mean + relu -> h1 in bf16 (u32 = 2 cols). Sums in fp32.
// Direct layout: node nn's messages at rows [nn*16, nn*16+cnt) -> contiguous.
__global__ void reduce1_kernel(const unsigned int* __restrict__ msg1,
                               const int* __restrict__ dcnt,
                               unsigned int* __restrict__ h1bf) {
    int t = blockIdx.x * blockDim.x + threadIdx.x;   // over N_NODES*16
    if (t >= N_NODES * 16) return;
    int nn = t >> 4, cp = t & 15;
    int cnt = dcnt[nn];
    int km = cnt < CAPD ? cnt : CAPD;
    int s = nn << 4;
    float sx = 0.f, sy = 0.f;
    for (int k = 0; k < km; ++k) {
        unsigned v = msg1[(size_t)(s + k) * 16 + cp];   // row = 16 u32
        sx += bfl(v); sy += bfh(v);
    }
    float inv = 1.0f / fmaxf((float)cnt, 1.0f);
    unsigned lo = f2bf_u(fmaxf(sx * inv, 0.f));
    unsigned hi = f2bf_u(fmaxf(sy * inv, 0.f));
    h1bf[t] = lo | (hi << 16);
}

// ---------------------------------------------------------------------------
// Layer 2: 256-thread blocks (4 waves), same occupancy fix as layer 1.
// Gather bf16 h1 rows (16B/lane), 1 MFMA/tile; column pairing via shfl_xor
// -> one u32 store per even lane-row.
__global__ __launch_bounds__(64 * LW) void layer2_kernel(
        const unsigned short* __restrict__ h1bf,
        const unsigned short* __restrict__ pw2,
        const int* __restrict__ rcnt,
        const uint2* __restrict__ epack,
        unsigned int* __restrict__ msg2) {
    int r = blockIdx.x % R2, sg = blockIdx.x / R2;
    int lane = threadIdx.x & 63, w = threadIdx.x >> 6;
    int stripe = sg * LW + w;
    int cnt = rcnt[r];
    int nT = (cnt + 15) >> 4;
    int n = lane & 15, q = lane >> 4;
    short8 b = *(const short8*)(pw2 + (size_t)r * 512 + lane * 8);
    const uint2* ep = epack + ((size_t)r << 12);
    for (int g = stripe; g < nT; g += S2) {
        int base = g * 16;
        int cl = cnt - base;
        int me = n < cl ? n : cl - 1;
        uint2 E = ep[base + me];
        int s  = (int)(E.y & 0x1FFFFu);
        int pd = (int)((E.x >> 17) | ((E.y >> 17) << 15));
        short8 a = *(const short8*)(h1bf + (size_t)s * EMB + q * 8);
        f32x4 c = {0.f,0.f,0.f,0.f};
        c = __builtin_amdgcn_mfma_f32_16x16x32_bf16(a, b, c, 0, 0, 0);
#pragma unroll
        for (int i = 0; i < 4; ++i) {
            int row = q * 4 + i;
            int p = __shfl(pd, row);
            unsigned myb = (unsigned)f2bf_u(c[i]);
            unsigned ob  = (unsigned)__shfl_xor((int)myb, 1);
            if (row < cl && !(n & 1)) {
                msg2[(size_t)p * 8 + (n >> 1)] = myb | (ob << 16);  // cols (n, n+1)
            }
        }
    }
}

// ---------------------------------------------------------------------------
// Segmented mean + PonderNet head, fused; writes final fp32 output.
__global__ void reduce2_head_kernel(const unsigned int* __restrict__ msg2,
                                    const int* __restrict__ dcnt,
                                    const float* __restrict__ lw,
                                    const float* __restrict__ lb,
                                    float* __restrict__ out) {
    int nn = blockIdx.x * blockDim.x + threadIdx.x;
    if (nn >= N_NODES) return;
    int cnt = dcnt[nn];
    int km = cnt < CAPD ? cnt : CAPD;
    int s = nn << 4;
    float h[TYPES];
#pragma unroll
    for (int j = 0; j < TYPES; ++j) h[j] = 0.f;
    for (int k = 0; k < km; ++k) {
        const uint4* row = (const uint4*)(msg2 + (size_t)(s + k) * 8);  // 16 bf16
        uint4 A = row[0], B = row[1];
        h[0] += bfl(A.x);  h[1] += bfh(A.x);  h[2] += bfl(A.y);  h[3] += bfh(A.y);
        h[4] += bfl(A.z);  h[5] += bfh(A.z);  h[6] += bfl(A.w);  h[7] += bfh(A.w);
        h[8] += bfl(B.x);  h[9] += bfh(B.x);  h[10] += bfl(B.y); h[11] += bfh(B.y);
        h[12] += bfl(B.z); h[13] += bfh(B.z); h[14] += bfl(B.w); h[15] += bfh(B.w);
    }
    float inv = 1.0f / fmaxf((float)cnt, 1.0f);
    float dot = 0.f;
#pragma unroll
    for (int j = 0; j < TYPES; ++j) { h[j] *= inv; dot += h[j] * lw[j]; }
    dot += lb[0];
    float lam = 1.0f / (1.0f + expf(-dot));

    float4* y0 = (float4*)(out + (size_t)nn * TYPES);
    float4* y1 = (float4*)(out + (size_t)N_NODES * TYPES + (size_t)nn * TYPES);
#pragma unroll
    for (int j = 0; j < 4; ++j) {
        float4 v = { h[4*j], h[4*j+1], h[4*j+2], h[4*j+3] };
        y0[j] = v; y1[j] = v;
    }
    out[(size_t)2 * N_NODES * TYPES + nn] = lam;
    out[(size_t)2 * N_NODES * TYPES + N_NODES + nn] = 1.0f - lam;
}

// ---------------------------------------------------------------------------
extern "C" void kernel_launch(void* const* d_in, const int* in_sizes, int n_in,
                              void* d_out, int out_size, void* d_ws, size_t ws_size,
                              hipStream_t stream) {
    const float* entity = (const float*)d_in[0];
    const float* W1     = (const float*)d_in[1];
    const float* W2     = (const float*)d_in[2];
    const float* lw     = (const float*)d_in[3];
    const float* lb     = (const float*)d_in[4];
    const int* src_ids  = (const int*)d_in[5];
    const int* edge_src = (const int*)d_in[6];
    const int* edge_dst = (const int*)d_in[7];
    const int* etype    = (const int*)d_in[8];
    float* out = (float*)d_out;

    // ws layout (u32 units, all 16B aligned)
    unsigned int* W = (unsigned int*)d_ws;
    int* dcnt   = (int*)(W + 0);              // 100000  (zeroed)
    int* rcnt   = (int*)(W + 100000);         // 128     (zeroed)
    uint2* epack = (uint2*)(W + 100128);      // R2*CAP uint2 = 819,200 u32
    unsigned short* pw1 = (unsigned short*)(W + 919328);  // 51,200 u32
    unsigned short* pw2 = (unsigned short*)(W + 970528);  // 25,600 u32
    unsigned int* h1bf  = W + 996128;         // 1.6M u32
    unsigned int* msg1  = W + 2596128;        // N_NODES*CAPD*16 u32 = 25.6M u32
    unsigned int* msg2  = W + 28196128;       // N_NODES*CAPD*8  u32 = 12.8M u32
    // total: 40,996,128 u32 = 164 MB

    (void)hipMemsetAsync(d_ws, 0, 100128 * sizeof(int), stream);  // dcnt+rcnt

    pass1_kernel<<<NB + R2, SB, 0, stream>>>(etype, edge_src, edge_dst, src_ids,
                                             W1, W2, rcnt, dcnt, pw1, pw2, epack);
    layer1_kernel<<<R2 * (S1 / LW), 64 * LW, 0, stream>>>(
        entity, pw1, rcnt, epack, msg1);
    reduce1_kernel<<<(N_NODES * 16 + 255) / 256, 256, 0, stream>>>(msg1, dcnt, h1bf);
    layer2_kernel<<<R2 * (S2 / LW), 64 * LW, 0, stream>>>(
        (const unsigned short*)h1bf, pw2, rcnt, epack, msg2);
    reduce2_head_kernel<<<(N_NODES + 255) / 256, 256, 0, stream>>>(
        msg2, dcnt, lw, lb, out);
}